// Round 3
// baseline (557.892 us; speedup 1.0000x reference)
//
#include <hip/hip_runtime.h>
#include <math.h>

#define BB 4
#define SS 1024
#define HH 12
#define DD 32
#define HIDDEN 768
#define AHS 384
#define RQ 8
#define HEAD_ELEMS (SS*DD)      // 32768
#define CTX_ELEMS (BB*SS*AHS)   // 1572864

__device__ __forceinline__ float clampf(float x, float lo, float hi){ return fminf(fmaxf(x, lo), hi); }

// ---------------------------------------------------------------------------
// Kernel 1: fused QKV projection. C = X @ W^T + b, 4 weight mats as one
// [4096 x 1536] GEMM.
// Round-3 change: BM 128->64, BK 16->32. Grid 64x24 = 1536 WGs -> 6 WGs/CU
// (was 3), 24 waves/CU, half the barrier count. The old config was
// latency-bound at 3 waves/SIMD (proj ran ~230 us vs a ~61 us FMA floor).
// q,v stored [BH,S,D]; k1,k2 INTERLEAVED [BH, D/4, S, 4].
// ---------------------------------------------------------------------------
__global__ __launch_bounds__(256)
void proj_kernel(const float* __restrict__ X,
                 const float* __restrict__ W0, const float* __restrict__ b0,
                 const float* __restrict__ W1, const float* __restrict__ b1,
                 const float* __restrict__ W2, const float* __restrict__ b2,
                 const float* __restrict__ W3, const float* __restrict__ b3,
                 float* __restrict__ qo, float* __restrict__ k1o,
                 float* __restrict__ k2o, float* __restrict__ vo)
{
    const int BM = 64, BN = 64, BK = 32;
    __shared__ float Xs[BK][BM + 4];    // +4 keeps row base 16B-aligned
    __shared__ float Wsh[BK][BN + 4];
    int t  = threadIdx.x;
    int m0 = blockIdx.x * BM;
    int n0 = blockIdx.y * BN;
    int mat = n0 / AHS;                 // 6 tiles per mat, never straddles
    int c0  = n0 % AHS;
    const float* W    = (mat==0) ? W0 : (mat==1) ? W1 : (mat==2) ? W2 : W3;
    const float* bias = (mat==0) ? b0 : (mat==1) ? b1 : (mat==2) ? b2 : b3;

    int tx = t & 15, ty = t >> 4;       // micro-tile: rows ty*4..+4, cols tx*4..+4
    // staging: flat = i*256+t; row = flat>>3 (0..63), c = flat&7 (k-quad)
    int srow0 = t >> 3,          sc0 = (t & 7) << 2;
    int srow1 = (256 + t) >> 3,  sc1 = sc0;            // (256+t)&7 == t&7

    float acc[4][4];
    #pragma unroll
    for (int i = 0; i < 4; i++)
        #pragma unroll
        for (int j = 0; j < 4; j++) acc[i][j] = 0.f;

    float4 xr0 = *(const float4*)(X + (m0 + srow0) * HIDDEN + sc0);
    float4 xr1 = *(const float4*)(X + (m0 + srow1) * HIDDEN + sc1);
    float4 wr0 = *(const float4*)(W + (c0 + srow0) * HIDDEN + sc0);
    float4 wr1 = *(const float4*)(W + (c0 + srow1) * HIDDEN + sc1);

    for (int k0 = 0; k0 < HIDDEN; k0 += BK) {
        __syncthreads();
        Xs[sc0+0][srow0] = xr0.x; Xs[sc0+1][srow0] = xr0.y;
        Xs[sc0+2][srow0] = xr0.z; Xs[sc0+3][srow0] = xr0.w;
        Xs[sc1+0][srow1] = xr1.x; Xs[sc1+1][srow1] = xr1.y;
        Xs[sc1+2][srow1] = xr1.z; Xs[sc1+3][srow1] = xr1.w;
        Wsh[sc0+0][srow0] = wr0.x; Wsh[sc0+1][srow0] = wr0.y;
        Wsh[sc0+2][srow0] = wr0.z; Wsh[sc0+3][srow0] = wr0.w;
        Wsh[sc1+0][srow1] = wr1.x; Wsh[sc1+1][srow1] = wr1.y;
        Wsh[sc1+2][srow1] = wr1.z; Wsh[sc1+3][srow1] = wr1.w;
        __syncthreads();
        if (k0 + BK < HIDDEN) {   // prefetch next tile during compute
            xr0 = *(const float4*)(X + (m0 + srow0) * HIDDEN + k0 + BK + sc0);
            xr1 = *(const float4*)(X + (m0 + srow1) * HIDDEN + k0 + BK + sc1);
            wr0 = *(const float4*)(W + (c0 + srow0) * HIDDEN + k0 + BK + sc0);
            wr1 = *(const float4*)(W + (c0 + srow1) * HIDDEN + k0 + BK + sc1);
        }
        #pragma unroll
        for (int kk = 0; kk < BK; kk++) {
            float a[4], w4[4];
            *(float4*)a  = *(const float4*)&Xs[kk][ty << 2];
            *(float4*)w4 = *(const float4*)&Wsh[kk][tx << 2];
            #pragma unroll
            for (int i = 0; i < 4; i++)
                #pragma unroll
                for (int j = 0; j < 4; j++)
                    acc[i][j] = fmaf(a[i], w4[j], acc[i][j]);
        }
    }

    int cbase = c0 + (tx << 2);          // < 384; one d-quad of one head
    int h  = cbase >> 5;
    int d0 = cbase & 31;
    int d4 = d0 >> 2;
    float4 bq4 = *(const float4*)(bias + cbase);

    #pragma unroll
    for (int i = 0; i < 4; i++) {
        int row = m0 + (ty << 2) + i;
        int b_  = row >> 10;
        int s   = row & 1023;
        int bh  = b_ * HH + h;
        float4 val;
        val.x = acc[i][0] + bq4.x;
        val.y = acc[i][1] + bq4.y;
        val.z = acc[i][2] + bq4.z;
        val.w = acc[i][3] + bq4.w;
        if (mat == 0)
            *(float4*)&qo[((size_t)(bh * SS + s)) * DD + d0] = val;
        else if (mat == 1)
            *(float4*)&k1o[((size_t)(bh * 8 + d4) * SS + s) * 4] = val;
        else if (mat == 2)
            *(float4*)&k2o[((size_t)(bh * 8 + d4) * SS + s) * 4] = val;
        else
            *(float4*)&vo[((size_t)(bh * SS + s)) * DD + d0] = val;
    }
}

// ---------------------------------------------------------------------------
// Kernel 2: per-row squared norms of k1,k2 from the interleaved layout.
// ---------------------------------------------------------------------------
__global__ __launch_bounds__(256)
void norms_kernel(const float* __restrict__ k1i, const float* __restrict__ k2i,
                  float* __restrict__ n1, float* __restrict__ n2)
{
    int bh = blockIdx.y;
    int s  = blockIdx.x * 256 + threadIdx.x;
    const float* p1 = k1i + (size_t)bh * (8 * SS * 4) + s * 4;
    const float* p2 = k2i + (size_t)bh * (8 * SS * 4) + s * 4;
    float a1 = 0.f, a2 = 0.f;
    #pragma unroll
    for (int d4 = 0; d4 < 8; d4++) {
        float4 v1 = *(const float4*)&p1[(size_t)d4 * SS * 4];
        float4 v2 = *(const float4*)&p2[(size_t)d4 * SS * 4];
        a1 = fmaf(v1.x, v1.x, a1); a1 = fmaf(v1.y, v1.y, a1);
        a1 = fmaf(v1.z, v1.z, a1); a1 = fmaf(v1.w, v1.w, a1);
        a2 = fmaf(v2.x, v2.x, a2); a2 = fmaf(v2.y, v2.y, a2);
        a2 = fmaf(v2.z, v2.z, a2); a2 = fmaf(v2.w, v2.w, a2);
    }
    n1[bh * SS + s] = a1;
    n2[bh * SS + s] = a2;
}

// ---------------------------------------------------------------------------
// Kernel 3: FUSED scores + softmax-mixture + ctx = P @ V + probs write.
// Round-3 change: probs NT stores moved from phase 3 (where the following
// __syncthreads drained vmcnt(0) and stalled the WG on HBM store completion
// -- VALUBusy dropped 89->75% in round 2) to AFTER phase 4, where no barrier
// follows. P values are re-emitted from the still-live e1r/inv registers.
// ---------------------------------------------------------------------------
__global__ __launch_bounds__(256, 4)
void attn_fused(const float* __restrict__ qg,  const float* __restrict__ k1i,
                const float* __restrict__ k2i,
                const float* __restrict__ n1g, const float* __restrict__ n2g,
                const float* __restrict__ maskg, const float* __restrict__ pig,
                const float* __restrict__ vg,
                float* __restrict__ probs, float* __restrict__ ctx)
{
    const float A1C = 0.08838834764831845f;   // SCALING/2
    const float A2C = 0.13258252147247767f;   // 1.5*SCALING/2
    __shared__ float p_s[RQ * SS];            // 32 KB: P tile, then PV partials
    __shared__ float q_s[RQ * DD];
    __shared__ float red1[4][RQ], red2[4][RQ];
    __shared__ float qn_s[RQ];

    int t    = threadIdx.x;
    int lane = t & 63, wid = t >> 6;

    // XCD swizzle: 6144 blocks, 8 XCDs -> each XCD gets 768 consecutive
    // swizzled ids = 6 consecutive bh values (k1+k2+v = 2.3 MB, fits 4 MB L2).
    int bid = blockIdx.x;
    int swz = (bid & 7) * 768 + (bid >> 3);
    int bh  = swz >> 7;
    int s0  = (swz & 127) * RQ;
    int b   = bh / HH, h = bh - b * HH;

    q_s[t] = qg[(bh * SS + s0) * DD + t];
    __syncthreads();
    if (t < RQ) {
        float a = 0.f;
        for (int d = 0; d < DD; d++) { float x = q_s[t * DD + d]; a = fmaf(x, x, a); }
        qn_s[t] = a;
    }
    __syncthreads();

    float pi0 = clampf(pig[h],      1e-6f, 2.0f);
    float pi1 = clampf(pig[HH + h], 1e-6f, 2.0f);

    float e1r[4][RQ], e2r[4][RQ];
    float pm1[RQ], pm2[RQ];
    #pragma unroll
    for (int r = 0; r < RQ; r++) { pm1[r] = -3.4e38f; pm2[r] = -3.4e38f; }

    const float* k1p = k1i + (size_t)bh * (8 * SS * 4);   // [d4][s][4]
    const float* k2p = k2i + (size_t)bh * (8 * SS * 4);
    const float* n1p = n1g + bh * SS;
    const float* n2p = n2g + bh * SS;
    const float* mp  = maskg + b * SS;

    // ---- phase 1: dots + scores -------------------------------------------
    #pragma unroll
    for (int j = 0; j < 4; j++) {
        int k = j * 256 + t;
        float n1k = n1p[k], n2k = n2p[k], mk = mp[k];
        float c1[RQ], c2[RQ];
        #pragma unroll
        for (int r = 0; r < RQ; r++) { c1[r] = 0.f; c2[r] = 0.f; }
        #pragma unroll
        for (int d4 = 0; d4 < 8; d4++) {
            float4 kq1 = *(const float4*)&k1p[((size_t)d4 * SS + k) * 4];
            float4 kq2 = *(const float4*)&k2p[((size_t)d4 * SS + k) * 4];
            const float* kv1 = (const float*)&kq1;
            const float* kv2 = (const float*)&kq2;
            #pragma unroll
            for (int r = 0; r < RQ; r++) {
                float qv[4];
                *(float4*)qv = *(const float4*)&q_s[r * DD + d4 * 4];
                #pragma unroll
                for (int dd = 0; dd < 4; dd++) {
                    c1[r] = fmaf(qv[dd], kv1[dd], c1[r]);
                    c2[r] = fmaf(qv[dd], kv2[dd], c2[r]);
                }
            }
        }
        #pragma unroll
        for (int r = 0; r < RQ; r++) {
            float qn  = qn_s[r];
            float d1v = fmaxf(fmaf(-2.f, c1[r], qn + n1k), 0.f);
            float d2v = fmaxf(fmaf(-2.f, c2[r], qn + n2k), 0.f);
            float ev1 = fmaf(-A1C, d1v, mk);
            float ev2 = fmaf(-A2C, d2v, mk);
            e1r[j][r] = ev1;
            e2r[j][r] = ev2;
            pm1[r] = fmaxf(pm1[r], ev1);
            pm2[r] = fmaxf(pm2[r], ev2);
        }
    }

    // ---- row max (both sets, one barrier pair) ----------------------------
    #pragma unroll
    for (int off = 32; off >= 1; off >>= 1)
        #pragma unroll
        for (int r = 0; r < RQ; r++) {
            pm1[r] = fmaxf(pm1[r], __shfl_xor(pm1[r], off));
            pm2[r] = fmaxf(pm2[r], __shfl_xor(pm2[r], off));
        }
    if (lane == 0) {
        #pragma unroll
        for (int r = 0; r < RQ; r++) { red1[wid][r] = pm1[r]; red2[wid][r] = pm2[r]; }
    }
    __syncthreads();
    float m1[RQ], m2[RQ];
    #pragma unroll
    for (int r = 0; r < RQ; r++) {
        m1[r] = fmaxf(fmaxf(red1[0][r], red1[1][r]), fmaxf(red1[2][r], red1[3][r]));
        m2[r] = fmaxf(fmaxf(red2[0][r], red2[1][r]), fmaxf(red2[2][r], red2[3][r]));
    }

    // ---- phase 2: exp + mixture, row sums ---------------------------------
    float ps[RQ];
    #pragma unroll
    for (int r = 0; r < RQ; r++) ps[r] = 0.f;
    #pragma unroll
    for (int j = 0; j < 4; j++)
        #pragma unroll
        for (int r = 0; r < RQ; r++) {
            float p = pi0 * __expf(e1r[j][r] - m1[r]) + pi1 * __expf(e2r[j][r] - m2[r]);
            e1r[j][r] = p;
            ps[r] += p;
        }

    #pragma unroll
    for (int off = 32; off >= 1; off >>= 1)
        #pragma unroll
        for (int r = 0; r < RQ; r++) ps[r] += __shfl_xor(ps[r], off);
    __syncthreads();
    if (lane == 0) {
        #pragma unroll
        for (int r = 0; r < RQ; r++) red1[wid][r] = ps[r];
    }
    __syncthreads();
    float inv[RQ];
    #pragma unroll
    for (int r = 0; r < RQ; r++) {
        float sum = red1[0][r] + red1[1][r] + red1[2][r] + red1[3][r];
        inv[r] = 1.0f / (sum + 1e-6f);
    }

    // ---- phase 3: normalize + stash P in LDS (NO global store here) -------
    // LDS layout: element (k, r) at float index ((k<<3)+r) ^ (((k>>5)&3)<<3).
    #pragma unroll
    for (int j = 0; j < 4; j++) {
        int k = (j << 8) + t;
        float pv8[8];
        #pragma unroll
        for (int r = 0; r < RQ; r++) pv8[r] = e1r[j][r] * inv[r];
        int base = (k << 3) ^ (((k >> 5) & 3) << 3);
        *(float4*)&p_s[base]     = *(float4*)&pv8[0];
        *(float4*)&p_s[base + 4] = *(float4*)&pv8[4];
    }
    __syncthreads();

    // ---- phase 4a: partial PV. thread = (ks 0..31, c4 0..7) ---------------
    {
        int ks = t >> 3;                 // k slice: 32 consecutive k
        int c4 = t & 7;                  // d-quad: columns c4*4 .. +4
        int swzc = (ks & 3) << 3;
        const float* vp = vg + bh * HEAD_ELEMS + (c4 << 2);
        float4 acc4[RQ];
        #pragma unroll
        for (int r = 0; r < RQ; r++) acc4[r] = make_float4(0.f, 0.f, 0.f, 0.f);
        #pragma unroll 4
        for (int kk = 0; kk < 32; kk++) {
            int k = (ks << 5) + kk;
            int base = (k << 3) ^ swzc;
            float pr[8];
            *(float4*)&pr[0] = *(const float4*)&p_s[base];
            *(float4*)&pr[4] = *(const float4*)&p_s[base + 4];
            float4 vv = *(const float4*)&vp[k << 5];
            #pragma unroll
            for (int r = 0; r < RQ; r++) {
                acc4[r].x = fmaf(pr[r], vv.x, acc4[r].x);
                acc4[r].y = fmaf(pr[r], vv.y, acc4[r].y);
                acc4[r].z = fmaf(pr[r], vv.z, acc4[r].z);
                acc4[r].w = fmaf(pr[r], vv.w, acc4[r].w);
            }
        }
        __syncthreads();                 // all P reads done; reuse p_s
        // partials: element (ks, r, d) at ((ks<<8)+(r<<5)+d) ^ ((ks&3)<<3)
        #pragma unroll
        for (int r = 0; r < RQ; r++)
            *(float4*)&p_s[((ks << 8) + (r << 5) + (c4 << 2)) ^ ((ks & 3) << 3)] = acc4[r];
    }
    __syncthreads();

    // ---- phase 4b: cross-slice reduce + NT ctx store ----------------------
    {
        int rr = t >> 5, dd = t & 31;
        float o = 0.f;
        #pragma unroll
        for (int s2 = 0; s2 < 32; s2++)
            o += p_s[((s2 << 8) + (rr << 5) + dd) ^ ((s2 & 3) << 3)];
        __builtin_nontemporal_store(o, &ctx[((size_t)(b * SS + s0 + rr) * HH + h) * DD + dd]);
    }

    // ---- phase 5: NT probs stores, tail position (no barrier after) -------
    float* prow = probs + (size_t)(bh * SS + s0) * SS;
    #pragma unroll
    for (int j = 0; j < 4; j++) {
        int k = (j << 8) + t;
        #pragma unroll
        for (int r = 0; r < RQ; r++)
            __builtin_nontemporal_store(e1r[j][r] * inv[r], &prow[(size_t)r * SS + k]);
    }
}

// ---------------------------------------------------------------------------
extern "C" void kernel_launch(void* const* d_in, const int* in_sizes, int n_in,
                              void* d_out, int out_size, void* d_ws, size_t ws_size,
                              hipStream_t stream)
{
    const float* hs   = (const float*)d_in[0];
    const float* mask = (const float*)d_in[1];
    const float* Wq   = (const float*)d_in[2];
    const float* bq   = (const float*)d_in[3];
    const float* Wk1  = (const float*)d_in[4];
    const float* bk1  = (const float*)d_in[5];
    const float* Wk2  = (const float*)d_in[6];
    const float* bk2  = (const float*)d_in[7];
    const float* Wv   = (const float*)d_in[8];
    const float* bv   = (const float*)d_in[9];
    const float* pi   = (const float*)d_in[10];

    float* ws   = (float*)d_ws;
    float* q_ws = ws;
    float* v_ws = ws + (size_t)CTX_ELEMS * 1;
    float* k1T  = ws + (size_t)CTX_ELEMS * 2;
    float* k2T  = ws + (size_t)CTX_ELEMS * 3;
    float* n1   = ws + (size_t)CTX_ELEMS * 4;
    float* n2   = n1 + BB * HH * SS;

    float* ctx   = (float*)d_out;
    float* probs = ctx + CTX_ELEMS;

    proj_kernel<<<dim3(64, 24), 256, 0, stream>>>(hs, Wq, bq, Wk1, bk1, Wk2, bk2,
                                                  Wv, bv, q_ws, k1T, k2T, v_ws);
    norms_kernel<<<dim3(SS / 256, BB * HH), 256, 0, stream>>>(k1T, k2T, n1, n2);
    attn_fused<<<dim3(BB * HH * (SS / RQ)), 256, 0, stream>>>(q_ws, k1T, k2T,
                                                              n1, n2, mask, pi,
                                                              v_ws, probs, ctx);
}